// Round 4
// baseline (1344.549 us; speedup 1.0000x reference)
//
#include <hip/hip_runtime.h>
#include <math.h>

// Problem constants (from reference: B=4, S=1024, D=512, COMP=4)
#define S 1024
#define D 512
#define NCOMP (S / 4)        // 256
#define STEPS (S - NCOMP)    // 768
#define NEG_INF (-__builtin_inff())

__device__ __forceinline__ int   f2i(float x) { return __builtin_bit_cast(int, x); }
__device__ __forceinline__ float i2f(int x)   { return __builtin_bit_cast(float, x); }
__device__ __forceinline__ int   rfl(int x)   { return __builtin_amdgcn_readfirstlane(x); }

// Monotone float->uint key (strictly >0 for any non-NaN float).
__device__ __forceinline__ unsigned fkey(float f) {
    unsigned u = __builtin_bit_cast(unsigned, f);
    return (u & 0x80000000u) ? ~u : (u | 0x80000000u);
}
__device__ __forceinline__ float unfkey(unsigned k) {
    unsigned u = (k & 0x80000000u) ? (k & 0x7fffffffu) : ~k;
    return __builtin_bit_cast(float, u);
}

// Full-wave sum via DPP; total lands in lane 63. Same order as rounds 1-3.
__device__ __forceinline__ float wave_sum63(float x) {
    x += i2f(__builtin_amdgcn_update_dpp(0, f2i(x), 0x111, 0xF, 0xF, true));
    x += i2f(__builtin_amdgcn_update_dpp(0, f2i(x), 0x112, 0xF, 0xF, true));
    x += i2f(__builtin_amdgcn_update_dpp(0, f2i(x), 0x114, 0xF, 0xF, true));
    x += i2f(__builtin_amdgcn_update_dpp(0, f2i(x), 0x118, 0xF, 0xF, true));
    x += i2f(__builtin_amdgcn_update_dpp(0, f2i(x), 0x142, 0xA, 0xF, true));
    x += i2f(__builtin_amdgcn_update_dpp(0, f2i(x), 0x143, 0xC, 0xF, true));
    return x;
}

#define AMAX_STEP(ctrl, rm) do {                                                        \
    unsigned ok_ = (unsigned)__builtin_amdgcn_update_dpp((int)key, (int)key, (ctrl), (rm), 0xF, false); \
    int      oi_ = __builtin_amdgcn_update_dpp(bi, bi, (ctrl), (rm), 0xF, false);        \
    bool tk_ = (ok_ > key) || ((ok_ == key) && (oi_ < bi));                              \
    key = tk_ ? ok_ : key; bi = tk_ ? oi_ : bi;                                          \
} while (0)

struct Row { float4 a, b; };

__device__ __forceinline__ Row row_load(const float* vals, int slot, int lane) {
    const float4* p = (const float4*)(vals + (size_t)slot * D);
    Row r; r.a = p[lane * 2]; r.b = p[lane * 2 + 1]; return r;
}
__device__ __forceinline__ void row_store(float* vals, int slot, int lane, Row r) {
    float4* p = (float4*)(vals + (size_t)slot * D);
    p[lane * 2] = r.a; p[lane * 2 + 1] = r.b;
}
__device__ __forceinline__ Row row_avg(Row x, Row y) {
    Row r;
    r.a.x = (x.a.x + y.a.x) * 0.5f; r.a.y = (x.a.y + y.a.y) * 0.5f;
    r.a.z = (x.a.z + y.a.z) * 0.5f; r.a.w = (x.a.w + y.a.w) * 0.5f;
    r.b.x = (x.b.x + y.b.x) * 0.5f; r.b.y = (x.b.y + y.b.y) * 0.5f;
    r.b.z = (x.b.z + y.b.z) * 0.5f; r.b.w = (x.b.w + y.b.w) * 0.5f;
    return r;
}
// Fixed accumulation order (identical to rounds 1-3).
__device__ __forceinline__ float dot8_partial(Row x, Row y) {
    float acc = x.a.x * y.a.x;
    acc += x.a.y * y.a.y; acc += x.a.z * y.a.z; acc += x.a.w * y.a.w;
    acc += x.b.x * y.b.x; acc += x.b.y * y.b.y; acc += x.b.z * y.b.z; acc += x.b.w * y.b.w;
    return acc;
}
__device__ __forceinline__ int lsr(int s) { return ((unsigned)s < (unsigned)S) ? s : 0; }
__device__ __forceinline__ int lsl(int s) { return ((unsigned)s <= (unsigned)S) ? s : 0; }

// 16-value max tree, ties -> smallest k. Returns (cm, ca).
__device__ __forceinline__ void tree16(const float (&av)[16], float& cm, int& ca) {
    float v8[8]; int k8[8];
#pragma unroll
    for (int k = 0; k < 8; ++k) { bool tk = av[k+8] > av[k]; v8[k] = tk ? av[k+8] : av[k]; k8[k] = tk ? (k+8) : k; }
    float v4[4]; int k4[4];
#pragma unroll
    for (int k = 0; k < 4; ++k) { bool tk = v8[k+4] > v8[k]; v4[k] = tk ? v8[k+4] : v8[k]; k4[k] = tk ? k8[k+4] : k8[k]; }
    float v2[2]; int k2[2];
#pragma unroll
    for (int k = 0; k < 2; ++k) { bool tk = v4[k+2] > v4[k]; v2[k] = tk ? v4[k+2] : v4[k]; k2[k] = tk ? k4[k+2] : k4[k]; }
    bool tk1 = v2[1] > v2[0];
    cm = tk1 ? v2[1] : v2[0];
    ca = tk1 ? k2[1] : k2[0];
}

__global__ __launch_bounds__(512, 1) void pool_kernel(const float* __restrict__ x,
                                                      float* __restrict__ out,
                                                      float* vals_base) {
    const int b = blockIdx.x, tid = threadIdx.x, lane = tid & 63, wave = tid >> 6;
    float* vb = vals_base + (size_t)b * S * D;
    const float* xb = x + (size_t)b * S * D;

    __shared__ int4  links[S + 1];   // {prv, nxt, nxt2(clamped to S), pad}
    __shared__ float dist[S];
    __shared__ float mbA[2];         // W1 -> W0: {ndp, ndm}
    __shared__ int   mbB[4];         // W0 -> W1: {m, p, r, q}
    __shared__ int   outIdx[NCOMP];

    // ---- init: copy (warms this block's own XCD L2) + links ----
    if (vals_base != x) {
        const float4* s4 = (const float4*)xb;
        float4* d4 = (float4*)vb;
        for (int i = tid; i < S * D / 4; i += 512) d4[i] = s4[i];
    }
    for (int s = tid; s <= S; s += 512)
        links[s] = (s == S) ? make_int4(S, S, S, 0)
                            : make_int4(s - 1, s + 1, (s + 2 <= S) ? (s + 2) : S, 0);
    __syncthreads();

    // ---- init: 1023 adjacent-pair dots (8 waves) ----
    for (int pr = wave; pr < S - 1; pr += 8) {
        Row A = row_load(vb, pr, lane);
        Row B = row_load(vb, pr + 1, lane);
        float t_ = wave_sum63(dot8_partial(A, B));
        if (lane == 63) dist[pr] = t_;
    }
    if (tid == 0) dist[S - 1] = NEG_INF;
    __syncthreads();

    // ---- bootstrap (W0): colmax + first decision ----
    float cm = NEG_INF; int ca = 0;
    int m = 0, p = -1, r = 0, q = S, pp = -1, nq = S;
    bool hasp = false, hasq = false;
    if (wave == 0) {
        float av[16];
#pragma unroll
        for (int k = 0; k < 16; ++k) av[k] = dist[lane + 64 * k];
        tree16(av, cm, ca);
        unsigned key = fkey(cm); int bi = lane | (ca << 6);
        AMAX_STEP(0x111, 0xF); AMAX_STEP(0x112, 0xF);
        AMAX_STEP(0x114, 0xF); AMAX_STEP(0x118, 0xF);
        AMAX_STEP(0x142, 0xA); AMAX_STEP(0x143, 0xC);
        m = __builtin_amdgcn_readlane(bi, 63);
        int4 Lm = links[m];
        p = rfl(Lm.x); r = rfl(Lm.y); q = rfl(Lm.z);
        hasp = (p >= 0); hasq = (q < S);
        pp = hasp ? rfl(links[lsl(p)].x) : -1;
        nq = rfl(links[r].z);              // nxt2[r] == nxt[q] (clamped)
        if (lane == 0) { mbB[0] = m; mbB[1] = p; mbB[2] = r; mbB[3] = q; }
    }
    __syncthreads();

    // ---- main loop: W1 = rows+dots, W0 = argmax+links+decision ----
    int pm = -7, ppv = -7, pqv = -7;     // W1 persistent (sentinels never match)
    Row vmP, RpP, RqP;
#pragma unroll 1
    for (int t = 0; t < STEPS; ++t) {
        int i1v = 0, pi = -1, ri = 0, qi = S;  // W0 window-A -> window-B carriers
        float v1 = NEG_INF;
        if (wave == 1) {
            int m1 = rfl(mbB[0]), p1 = rfl(mbB[1]), r1 = rfl(mbB[2]), q1 = rfl(mbB[3]);
            bool h_p = (p1 >= 0), h_q = (q1 < S);
            Row Rm, Rr, Rp, Rq;
            if (m1 == pm) {          // consecutive merge to the right: (m, q)
                Rm = vmP; Rr = RqP; Rp = RpP;
                Rq = row_load(vb, lsr(q1), lane);
            } else if (r1 == pm) {   // consecutive merge to the left: (p, vm)
                Rm = RpP; Rr = vmP; Rq = RqP;
                Rp = row_load(vb, lsr(p1), lane);
            } else {                 // fresh site (only slot pm's row changed)
                Rm = row_load(vb, m1, lane);
                Rr = row_load(vb, r1, lane);
                Rp = (p1 == pm) ? vmP : row_load(vb, lsr(p1), lane);
                Rq = (q1 == pm) ? vmP : row_load(vb, lsr(q1), lane);
            }
            Row vm = row_avg(Rm, Rr);
            row_store(vb, m1, lane, vm);
            float sp = wave_sum63(dot8_partial(Rp, vm));
            float sq = wave_sum63(dot8_partial(vm, Rq));
            if (lane == 63) { mbA[0] = h_p ? sp : NEG_INF; mbA[1] = h_q ? sq : NEG_INF; }
            pm = m1; ppv = p1; pqv = q1; vmP = vm; RpP = Rp; RqP = Rq;
            (void)ppv; (void)pqv;
        } else if (wave == 0) {
            // window A: poison + masked colmax recompute + static argmax + links
            if (lane == 0) {
                if (hasp) dist[p] = NEG_INF;
                dist[m] = NEG_INF; dist[r] = NEG_INF;
            }
            bool needR = (lane == (m & 63) && ca == (m >> 6)) ||
                         (lane == (r & 63) && ca == (r >> 6)) ||
                         (hasp && lane == (p & 63) && ca == (p >> 6));
            if (needR) {
                float av[16];
#pragma unroll
                for (int k = 0; k < 16; ++k) av[k] = dist[lane + 64 * k];
                tree16(av, cm, ca);
            }
            if (lane == 0) {
                links[m].y = q; links[m].z = nq;
                if (hasp) links[p].z = q;
                if (hasq) links[q].x = m;
            }
            unsigned key = fkey(cm); int bi = lane | (ca << 6);
            AMAX_STEP(0x111, 0xF); AMAX_STEP(0x112, 0xF);
            AMAX_STEP(0x114, 0xF); AMAX_STEP(0x118, 0xF);
            AMAX_STEP(0x142, 0xA); AMAX_STEP(0x143, 0xC);
            i1v = __builtin_amdgcn_readlane(bi, 63);
            v1  = unfkey((unsigned)__builtin_amdgcn_readlane((int)key, 63));
            int4 Li = links[i1v];                 // post-update links: safe for i1
            pi = rfl(Li.x); ri = rfl(Li.y); qi = rfl(Li.z);
        }
        __syncthreads();   // S1: mbA visible to W0
        if (wave == 0) {
            float ndp = mbA[0], ndm = mbA[1];
            if (lane == 0) {
                if (hasp) dist[p] = ndp;
                if (hasq) dist[m] = ndm;
            }
            if (hasp && lane == (p & 63)) {
                int kp = p >> 6;
                if (ndp > cm || (ndp == cm && kp < ca)) { cm = ndp; ca = kp; }
            }
            if (hasq && lane == (m & 63)) {
                int km = m >> 6;
                if (ndm > cm || (ndm == cm && km < ca)) { cm = ndm; ca = km; }
            }
            // exact fixup: best of static winner and the two fresh candidates
            float best = v1; int b2 = i1v;
            if (hasp && (ndp > best || (ndp == best && p < b2))) { best = ndp; b2 = p; }
            if (hasq && (ndm > best || (ndm == best && m < b2))) { best = ndm; b2 = m; }
            int m2 = rfl(b2);
            int p2, r2, q2;
            if (m2 == m)      { p2 = p;  r2 = q; q2 = nq; }
            else if (m2 == p) { p2 = pp; r2 = m; q2 = q;  }
            else              { p2 = pi; r2 = ri; q2 = qi; }
            int pp2 = (p2 >= 0) ? rfl(links[lsl(p2)].x) : -1;
            int nq2 = rfl(links[r2].z);           // = nxt[q2] (clamped)
            if (lane == 0) { mbB[0] = m2; mbB[1] = p2; mbB[2] = r2; mbB[3] = q2; }
            m = m2; p = p2; r = r2; q = q2; pp = pp2; nq = nq2;
            hasp = (p >= 0); hasq = (q < S);
        }
        __syncthreads();   // S2: mbB visible to W1
    }

    // ---- output order: walk nxt/nxt2 (2 slots per LDS read) ----
    if (wave == 0 && lane == 0) {
        int s = 0;   // slot 0 is never removed (never a right token)
        for (int i = 0; i < NCOMP; i += 2) {
            int4 Ls = links[s];
            outIdx[i] = s;
            if (i + 1 < NCOMP) outIdx[i + 1] = Ls.y;
            s = Ls.z;
        }
    }
    __syncthreads();

    // ---- gather (8 waves) ----
    float* ob = out + (size_t)b * NCOMP * D;
    for (int i = wave; i < NCOMP; i += 8) {
        Row rr = row_load(vb, outIdx[i], lane);
        row_store(ob, i, lane, rr);
    }
}

extern "C" void kernel_launch(void* const* d_in, const int* in_sizes, int n_in,
                              void* d_out, int out_size, void* d_ws, size_t ws_size,
                              hipStream_t stream) {
    const float* x = (const float*)d_in[0];
    float* out = (float*)d_out;
    const int b = in_sizes[0] / (S * D);   // 4
    const size_t need = (size_t)in_sizes[0] * sizeof(float);
    float* vals = (ws_size >= need) ? (float*)d_ws : (float*)x;
    pool_kernel<<<dim3(b), dim3(512), 0, stream>>>(x, out, vals);
}

// Round 5
// 1092.480 us; speedup vs baseline: 1.2307x; 1.2307x over previous
//
#include <hip/hip_runtime.h>
#include <math.h>

// Problem constants (from reference: B=4, S=1024, D=512, COMP=4)
#define S 1024
#define D 512
#define NCOMP (S / 4)        // 256
#define STEPS (S - NCOMP)    // 768
#define NEG_INF (-__builtin_inff())

__device__ __forceinline__ int   f2i(float x) { return __builtin_bit_cast(int, x); }
__device__ __forceinline__ float i2f(int x)   { return __builtin_bit_cast(float, x); }
__device__ __forceinline__ int   rfl(int x)   { return __builtin_amdgcn_readfirstlane(x); }

// Monotone float->uint key; strictly > 0 for every non-NaN float, so key 0
// means "dead slot" and can never win an argmax against any real value.
__device__ __forceinline__ unsigned fkey(float f) {
    unsigned u = __builtin_bit_cast(unsigned, f);
    return (u & 0x80000000u) ? ~u : (u | 0x80000000u);
}

// Full-wave float sum via DPP; total lands in lane 63. Same order as r1-r4.
__device__ __forceinline__ float wave_sum63(float x) {
    x += i2f(__builtin_amdgcn_update_dpp(0, f2i(x), 0x111, 0xF, 0xF, true));
    x += i2f(__builtin_amdgcn_update_dpp(0, f2i(x), 0x112, 0xF, 0xF, true));
    x += i2f(__builtin_amdgcn_update_dpp(0, f2i(x), 0x114, 0xF, 0xF, true));
    x += i2f(__builtin_amdgcn_update_dpp(0, f2i(x), 0x118, 0xF, 0xF, true));
    x += i2f(__builtin_amdgcn_update_dpp(0, f2i(x), 0x142, 0xA, 0xF, true));
    x += i2f(__builtin_amdgcn_update_dpp(0, f2i(x), 0x143, 0xC, 0xF, true));
    return x;
}

// Full-wave unsigned max via DPP; result lands in lane 63. Unwritten/invalid
// lanes contribute 0 = identity (all live keys > 0).
__device__ __forceinline__ unsigned wave_max63(unsigned x) {
#define MAXD(c, rm) { unsigned o_ = (unsigned)__builtin_amdgcn_update_dpp(0, (int)x, (c), (rm), 0xF, true); x = (x > o_) ? x : o_; }
    MAXD(0x111, 0xF) MAXD(0x112, 0xF) MAXD(0x114, 0xF)
    MAXD(0x118, 0xF) MAXD(0x142, 0xA) MAXD(0x143, 0xC)
#undef MAXD
    return x;
}

struct Row { float4 a, b; };

__device__ __forceinline__ Row row_load(const float* vals, int slot, int lane) {
    const float4* p = (const float4*)(vals + (size_t)slot * D);
    Row r; r.a = p[lane * 2]; r.b = p[lane * 2 + 1]; return r;
}
__device__ __forceinline__ void row_store(float* vals, int slot, int lane, Row r) {
    float4* p = (float4*)(vals + (size_t)slot * D);
    p[lane * 2] = r.a; p[lane * 2 + 1] = r.b;
}
__device__ __forceinline__ Row row_avg(Row x, Row y) {
    Row r;
    r.a.x = (x.a.x + y.a.x) * 0.5f; r.a.y = (x.a.y + y.a.y) * 0.5f;
    r.a.z = (x.a.z + y.a.z) * 0.5f; r.a.w = (x.a.w + y.a.w) * 0.5f;
    r.b.x = (x.b.x + y.b.x) * 0.5f; r.b.y = (x.b.y + y.b.y) * 0.5f;
    r.b.z = (x.b.z + y.b.z) * 0.5f; r.b.w = (x.b.w + y.b.w) * 0.5f;
    return r;
}
// Fixed accumulation order (identical to rounds 1-4).
__device__ __forceinline__ float dot8_partial(Row x, Row y) {
    float acc = x.a.x * y.a.x;
    acc += x.a.y * y.a.y; acc += x.a.z * y.a.z; acc += x.a.w * y.a.w;
    acc += x.b.x * y.b.x; acc += x.b.y * y.b.y; acc += x.b.z * y.b.z; acc += x.b.w * y.b.w;
    return acc;
}
__device__ __forceinline__ int lsr(int s) { return ((unsigned)s < (unsigned)S) ? s : 0; }
__device__ __forceinline__ int lsl(int s) { return ((unsigned)s <= (unsigned)S) ? s : 0; }

// 16-key max tree, ties -> smallest k (slot = lane*16 + k, so min-k = min slot
// within the lane).
__device__ __forceinline__ void tree16k(const unsigned (&av)[16], unsigned& cm, int& ca) {
    unsigned v8[8]; int k8[8];
#pragma unroll
    for (int k = 0; k < 8; ++k) { bool tk = av[k+8] > av[k]; v8[k] = tk ? av[k+8] : av[k]; k8[k] = tk ? (k+8) : k; }
    unsigned v4[4]; int k4[4];
#pragma unroll
    for (int k = 0; k < 4; ++k) { bool tk = v8[k+4] > v8[k]; v4[k] = tk ? v8[k+4] : v8[k]; k4[k] = tk ? k8[k+4] : k8[k]; }
    unsigned v2[2]; int k2[2];
#pragma unroll
    for (int k = 0; k < 2; ++k) { bool tk = v4[k+2] > v4[k]; v2[k] = tk ? v4[k+2] : v4[k]; k2[k] = tk ? k4[k+2] : k4[k]; }
    bool tk1 = v2[1] > v2[0];
    cm = tk1 ? v2[1] : v2[0];
    ca = tk1 ? k2[1] : k2[0];
}

// Register-dist update: slot/key are wave-uniform; one lane's one register.
__device__ __forceinline__ void upd(unsigned (&av)[16], int lane, int slot, unsigned key) {
    if (lane == (slot >> 4)) {
        switch (slot & 15) {
            case 0:  av[0]  = key; break;  case 1:  av[1]  = key; break;
            case 2:  av[2]  = key; break;  case 3:  av[3]  = key; break;
            case 4:  av[4]  = key; break;  case 5:  av[5]  = key; break;
            case 6:  av[6]  = key; break;  case 7:  av[7]  = key; break;
            case 8:  av[8]  = key; break;  case 9:  av[9]  = key; break;
            case 10: av[10] = key; break;  case 11: av[11] = key; break;
            case 12: av[12] = key; break;  case 13: av[13] = key; break;
            case 14: av[14] = key; break;  case 15: av[15] = key; break;
        }
    }
}

// ---- K1: copy x->vals (if needed) + all 1023 initial pair dots into aux ----
__global__ __launch_bounds__(256) void init_kernel(const float* __restrict__ x,
                                                   float* __restrict__ vals,
                                                   float* __restrict__ out) {
    const int blk = blockIdx.x, b = blk >> 4, g = blk & 15;
    const int tid = threadIdx.x, lane = tid & 63, w = tid >> 6;
    const float* xb = x + (size_t)b * S * D;
    if (vals != x) {
        float* vb = vals + (size_t)b * S * D;
        const float4* s4 = (const float4*)xb;
        float4* d4 = (float4*)vb;
        const int base = g * (S * D / 4 / 16);
        for (int i = tid; i < S * D / 4 / 16; i += 256) d4[base + i] = s4[base + i];
    }
    float* sd = out + (size_t)b * NCOMP * D;   // sdist staged in out chunk b
#pragma unroll 1
    for (int j = 0; j < 16; ++j) {
        int pr = g * 64 + w * 16 + j;
        if (pr < S - 1) {
            Row A = row_load(xb, pr, lane);
            Row B = row_load(xb, pr + 1, lane);
            float t = wave_sum63(dot8_partial(A, B));
            if (lane == 63) sd[pr] = t;
        }
    }
    if (g == 0 && tid == 0) sd[S - 1] = NEG_INF;
}

// ---- K2: the serial merge loop — one 64-lane wave per sample ----
__global__ __launch_bounds__(64, 1) void merge_kernel(float* __restrict__ vals,
                                                      float* __restrict__ out) {
    const int b = blockIdx.x, lane = threadIdx.x;
    float* vb = vals + (size_t)b * S * D;
    float* aux = out + (size_t)b * NCOMP * D;
    int* outIdx = (int*)(aux + S);

    __shared__ int4 links[S + 1];   // {prv, nxt, nxt2(clamped to S), pad}
    for (int s = lane; s <= S; s += 64)
        links[s] = (s >= S) ? make_int4(S, S, S, 0)
                            : make_int4(s - 1, s + 1, (s + 2 <= S) ? (s + 2) : S, 0);

    // dist as register-resident monotone keys; slot = lane*16 + k
    unsigned av[16];
    {
        const float4* sd4 = (const float4*)aux;
#pragma unroll
        for (int j = 0; j < 4; ++j) {
            float4 v = sd4[lane * 4 + j];
            av[4*j+0] = fkey(v.x); av[4*j+1] = fkey(v.y);
            av[4*j+2] = fkey(v.z); av[4*j+3] = fkey(v.w);
        }
    }

    // ---- bootstrap decision ----
    unsigned cm; int ca;
    tree16k(av, cm, ca);
    unsigned smax = (unsigned)__builtin_amdgcn_readlane((int)wave_max63(cm), 63);
    unsigned long long tied = __ballot(cm == smax);
    int wl = (int)__ffsll(tied) - 1;                 // lowest tied lane = min slot
    int m = rfl((wl << 4) | __builtin_amdgcn_readlane(ca, wl));
    int4 Lm = links[m];
    int p = rfl(Lm.x), r = rfl(Lm.y), q = rfl(Lm.z);
    int nq = rfl(links[lsl(q)].y);
    Row Rp = row_load(vb, lsr(p), lane);
    Row Rm = row_load(vb, m,      lane);
    Row Rr = row_load(vb, r,      lane);
    Row Rq = row_load(vb, lsr(q), lane);
    int mprev = -1;
    Row vmPrev = Rm;   // placeholder, never matched at t=0

#pragma unroll 1
    for (int t = 0; ; ++t) {
        const bool hasp = (p >= 0), hasq = (q < S);
        // rows whose slot == last merge site must come from registers (their
        // store may still be in flight; all older stores are provably drained)
        if (p == mprev) Rp = vmPrev;
        if (m == mprev) Rm = vmPrev;
        if (r == mprev) Rr = vmPrev;
        if (q == mprev) Rq = vmPrev;

        Row vm = row_avg(Rm, Rr);
        row_store(vb, m, lane, vm);

        float sp = wave_sum63(dot8_partial(Rp, vm));
        float sq = wave_sum63(dot8_partial(vm, Rq));
        unsigned ndpk = hasp ? fkey(i2f(__builtin_amdgcn_readlane(f2i(sp), 63))) : 0u;
        unsigned ndmk = hasq ? fkey(i2f(__builtin_amdgcn_readlane(f2i(sq), 63))) : 0u;

        // link maintenance (keeps nxt2[s] == nxt[nxt[s]] for all active s)
        if (lane == 0) {
            links[m].y = q; links[m].z = nq;
            if (hasp) links[p].z = q;
            if (hasq) links[q].x = m;
        }
        // register-dist updates: r dead; m/p get the fresh dots (or dead)
        upd(av, lane, r, 0u);
        upd(av, lane, m, ndmk);
        if (hasp) upd(av, lane, p, ndpk);

        if (t == STEPS - 1) break;

        // ---- decision: max-only DPP butterfly + ballot winner recovery ----
        tree16k(av, cm, ca);
        smax = (unsigned)__builtin_amdgcn_readlane((int)wave_max63(cm), 63);
        tied = __ballot(cm == smax);
        wl = (int)__ffsll(tied) - 1;
        int m2 = rfl((wl << 4) | __builtin_amdgcn_readlane(ca, wl));

        int4 L2 = links[m2];
        int p2 = rfl(L2.x), r2 = rfl(L2.y), q2 = rfl(L2.z);
        int nq2 = rfl(links[lsl(q2)].y);
        Rp = row_load(vb, lsr(p2), lane);
        Rm = row_load(vb, m2,      lane);
        Rr = row_load(vb, r2,      lane);
        Rq = row_load(vb, lsr(q2), lane);

        mprev = m; vmPrev = vm;
        m = m2; p = p2; r = r2; q = q2; nq = nq2;
    }

    // ---- output order: walk nxt/nxt2 (2 slots per LDS read) ----
    if (lane == 0) {
        int s = 0;   // slot 0 is never removed (never a right token)
        for (int i = 0; i < NCOMP; i += 2) {
            int4 Ls = links[s];
            outIdx[i] = s;
            if (i + 1 < NCOMP) outIdx[i + 1] = Ls.y;
            s = Ls.z;
        }
    }
}

// ---- K3: gather the first NCOMP surviving rows into out ----
__global__ __launch_bounds__(256) void gather_kernel(const float* __restrict__ vals,
                                                     float* __restrict__ out) {
    const int b = blockIdx.x, part = blockIdx.y;
    const float* vb = vals + (size_t)b * S * D;
    float* ob = out + (size_t)b * NCOMP * D;
    __shared__ int oi[NCOMP / 8];
    const int row0 = part * (NCOMP / 8);
    if (threadIdx.x < NCOMP / 8)
        oi[threadIdx.x] = ((const int*)(ob + S))[row0 + threadIdx.x];
    __syncthreads();
    const float4* v4 = (const float4*)vb;
    float4* o4 = (float4*)ob;
    const int per = (NCOMP / 8) * (D / 4);            // 4096 float4s per part
    for (int idx = threadIdx.x; idx < per; idx += 256) {
        int row = idx >> 7, c = idx & 127;
        o4[(size_t)(row0 + row) * (D / 4) + c] = v4[(size_t)oi[row] * (D / 4) + c];
    }
}

extern "C" void kernel_launch(void* const* d_in, const int* in_sizes, int n_in,
                              void* d_out, int out_size, void* d_ws, size_t ws_size,
                              hipStream_t stream) {
    const float* x = (const float*)d_in[0];
    float* out = (float*)d_out;
    const int b = in_sizes[0] / (S * D);   // 4
    const size_t need = (size_t)in_sizes[0] * sizeof(float);
    float* vals = (ws_size >= need) ? (float*)d_ws : (float*)x;
    init_kernel<<<dim3(16 * b), dim3(256), 0, stream>>>(x, vals, out);
    merge_kernel<<<dim3(b), dim3(64), 0, stream>>>(vals, out);
    gather_kernel<<<dim3(b, 8), dim3(256), 0, stream>>>(vals, out);
}